// Round 1
// baseline (185.645 us; speedup 1.0000x reference)
//
#include <hip/hip_runtime.h>
#include <hip/hip_bf16.h>

#define EPS 1e-4f
#define NAXIS 8
#define NKNOTS 16      // interior knots; 18 total x-positions, 17 segments
#define NSEG 17
// per-batch workspace layout (floats), stride 384:
//  [0..24)    pinv[a*3+c]
//  [24..48)   Acol[a*3+c]  (= A[c][a], transposed for axis-major access)
//  [48..56)   mins[a]
//  [56..64)   invdx[a]
//  [64..336)  seg[a*17+s] as float2 {coef, icept}: est = coef*f + icept
#define WS_STRIDE 384
#define TBL_N 336

__global__ void spline_prep(const float* __restrict__ ys,
                            const float* __restrict__ A,
                            float* __restrict__ ws) {
    const int b = blockIdx.x;
    const float* Ab  = A  + (size_t)b * 3 * NAXIS;     // A[c*8+a]
    const float* ysb = ys + (size_t)b * NAXIS * NKNOTS;
    float* w = ws + (size_t)b * WS_STRIDE;
    __shared__ double Ginv[9];
    const int tid = threadIdx.x;

    if (tid == 0) {
        // G = A A^T (3x3, symmetric), fp64 for safety
        double G[9];
        for (int i = 0; i < 3; ++i)
            for (int j = 0; j < 3; ++j) {
                double s = 0.0;
                for (int a = 0; a < NAXIS; ++a)
                    s += (double)Ab[i * NAXIS + a] * (double)Ab[j * NAXIS + a];
                G[i * 3 + j] = s;
            }
        const double g00 = G[0], g01 = G[1], g02 = G[2];
        const double g11 = G[4], g12 = G[5], g22 = G[8];
        const double det = g00 * (g11 * g22 - g12 * g12)
                         - g01 * (g01 * g22 - g12 * g02)
                         + g02 * (g01 * g12 - g11 * g02);
        const double inv = 1.0 / det;
        Ginv[0] = (g11 * g22 - g12 * g12) * inv;
        Ginv[1] = (g02 * g12 - g01 * g22) * inv;
        Ginv[2] = (g01 * g12 - g02 * g11) * inv;
        Ginv[3] = Ginv[1];
        Ginv[4] = (g00 * g22 - g02 * g02) * inv;
        Ginv[5] = (g02 * g01 - g00 * g12) * inv;
        Ginv[6] = Ginv[2];
        Ginv[7] = Ginv[5];
        Ginv[8] = (g00 * g11 - g01 * g01) * inv;
    }
    __syncthreads();

    if (tid < 24) {                 // pinv[a][c] = sum_i A[i][a] * Ginv[i][c]
        const int a = tid / 3, c = tid % 3;
        double s = 0.0;
        for (int i = 0; i < 3; ++i)
            s += (double)Ab[i * NAXIS + a] * Ginv[i * 3 + c];
        w[a * 3 + c]      = (float)s;
        w[24 + a * 3 + c] = Ab[c * NAXIS + a];   // Acol
    }
    if (tid < NAXIS) {
        const int a = tid;
        float mn = 0.f, mx = 0.f;
        for (int c = 0; c < 3; ++c) {
            const float v = Ab[c * NAXIS + a];
            mn += (v < 0.f) ? v : 0.f;
            mx += (v > 0.f) ? v : 0.f;
        }
        const float range = mx + EPS - mn;
        const float dx = range / 17.0f;
        w[48 + a] = mn;
        w[56 + a] = 1.0f / dx;
        float yf[NKNOTS + 2];
        yf[0] = mn;
        for (int k = 0; k < NKNOTS; ++k) yf[k + 1] = ysb[a * NKNOTS + k];
        yf[NKNOTS + 1] = mx;
        for (int s = 0; s < NSEG; ++s) {
            const float sl  = (yf[s + 1] - yf[s]) / dx;
            const float xhi = ((float)(s + 1) / 17.0f) * range + mn;
            // est = yhi - (xhi - f)*sl  ==  sl*f + (yhi - xhi*sl)
            w[64 + (a * NSEG + s) * 2 + 0] = sl;
            w[64 + (a * NSEG + s) * 2 + 1] = yf[s + 1] - xhi * sl;
        }
    }
}

__global__ __launch_bounds__(256) void spline_main(const float* __restrict__ raw,
                                                   const float* __restrict__ ws,
                                                   float* __restrict__ out,
                                                   int blocksPerBatch, int HW) {
    const int b    = blockIdx.x / blocksPerBatch;
    const int tile = blockIdx.x % blocksPerBatch;

    __shared__ float s[TBL_N];
    {
        const float* w = ws + (size_t)b * WS_STRIDE;
        for (int i = threadIdx.x; i < TBL_N; i += 256) s[i] = w[i];
    }
    __syncthreads();

    const float*  sp   = s;                       // pinv[a*3+c]
    const float*  sA   = s + 24;                  // Acol[a*3+c]
    const float*  smn  = s + 48;
    const float*  sid  = s + 56;
    const float2* sseg = (const float2*)(s + 64); // {coef, icept}[a*17+idx]

    const size_t base = (size_t)b * 3 * HW + (size_t)tile * 1024 + threadIdx.x * 4;
    const float4 r4 = *(const float4*)(raw + base);
    const float4 g4 = *(const float4*)(raw + base + HW);
    const float4 b4 = *(const float4*)(raw + base + 2 * (size_t)HW);

    float4 o0, o1, o2;
    float* o0p = &o0.x; float* o1p = &o1.x; float* o2p = &o2.x;
    const float* rp = &r4.x; const float* gp = &g4.x; const float* bp = &b4.x;

    #pragma unroll
    for (int p = 0; p < 4; ++p) {
        const float rc = rp[p], gc = gp[p], bc = bp[p];
        float a0 = 0.f, a1 = 0.f, a2 = 0.f;
        #pragma unroll
        for (int a = 0; a < NAXIS; ++a) {
            const float fa = fmaf(rc, sA[a * 3 + 0],
                             fmaf(gc, sA[a * 3 + 1], bc * sA[a * 3 + 2]));
            int idx = (int)floorf((fa - smn[a]) * sid[a]);
            idx = idx < 0 ? 0 : (idx > NKNOTS ? NKNOTS : idx);
            const float2 ci = sseg[a * NSEG + idx];
            const float est = fmaf(ci.x, fa, ci.y);
            a0 = fmaf(est, sp[a * 3 + 0], a0);
            a1 = fmaf(est, sp[a * 3 + 1], a1);
            a2 = fmaf(est, sp[a * 3 + 2], a2);
        }
        o0p[p] = a0; o1p[p] = a1; o2p[p] = a2;
    }

    *(float4*)(out + base)                  = o0;
    *(float4*)(out + base + HW)             = o1;
    *(float4*)(out + base + 2 * (size_t)HW) = o2;
}

extern "C" void kernel_launch(void* const* d_in, const int* in_sizes, int n_in,
                              void* d_out, int out_size, void* d_ws, size_t ws_size,
                              hipStream_t stream) {
    const float* raw = (const float*)d_in[0];
    const float* ys  = (const float*)d_in[1];
    const float* A   = (const float*)d_in[2];
    float* out = (float*)d_out;
    float* ws  = (float*)d_ws;

    const int B  = in_sizes[2] / (3 * NAXIS);        // 8
    const int HW = in_sizes[0] / (B * 3);            // 1024*1024
    const int blocksPerBatch = HW / 1024;            // 256 thr * 4 px

    spline_prep<<<B, 64, 0, stream>>>(ys, A, ws);
    spline_main<<<B * blocksPerBatch, 256, 0, stream>>>(raw, ws, out, blocksPerBatch, HW);
}